// Round 10
// baseline (551.551 us; speedup 1.0000x reference)
//
#include <hip/hip_runtime.h>
#include <cstdint>
#include <cstddef>

typedef _Float16 f16;
typedef f16 f16x8 __attribute__((ext_vector_type(8)));
typedef f16 f16x4 __attribute__((ext_vector_type(4)));
typedef float floatx4 __attribute__((ext_vector_type(4)));

#define GAS __attribute__((address_space(1)))
#define LAS __attribute__((address_space(3)))

static constexpr int LSEQ = 2048;
static constexpr int NH   = 8;
static constexpr int DH   = 64;
static constexpr int DM   = 512;
static constexpr int WIN  = 64;
static constexpr int MR   = 4 * LSEQ;  // 8192 rows (B*L)

// ------------------------------------------- prep: cast x->f16  +  transpose W->f16
__global__ __launch_bounds__(256) void prep_kernel(
    const float* __restrict__ x, f16* __restrict__ xb,
    const float* __restrict__ Wq, const float* __restrict__ Wk,
    const float* __restrict__ Wv, const float* __restrict__ Wo,
    f16* __restrict__ wt) {
    __shared__ float tile[32][33];
    int bid = blockIdx.x;
    if (bid < 4096) {
        int i = bid * 256 + threadIdx.x;
        float4 v = ((const float4*)x)[i];
        f16x4 o = { (f16)v.x, (f16)v.y, (f16)v.z, (f16)v.w };
        ((f16x4*)xb)[i] = o;
    } else {
        int id = bid - 4096;
        int z  = id >> 8, t = id & 255;
        const float* W = z == 0 ? Wq : z == 1 ? Wk : z == 2 ? Wv : Wo;
        f16* out = wt + (size_t)z * DM * DM;
        int c0 = (t & 15) * 32, r0 = (t >> 4) * 32;
        int tx = threadIdx.x & 31, ty = threadIdx.x >> 5;
        #pragma unroll
        for (int i = 0; i < 32; i += 8)
            tile[ty + i][tx] = W[(size_t)(r0 + ty + i) * DM + c0 + tx];
        __syncthreads();
        #pragma unroll
        for (int i = 0; i < 32; i += 8)
            out[(size_t)(c0 + ty + i) * DM + r0 + tx] = (f16)tile[tx][ty + i];
    }
}

// ---------------------------------------------------------------- GEMM (R5 best-known)
template <bool QKV>
__global__ __launch_bounds__(256, 2) void gemm_kernel(
    const f16* __restrict__ A, const f16* __restrict__ Bt_base,
    const float* __restrict__ b0, const float* __restrict__ b1,
    const float* __restrict__ b2,
    f16* __restrict__ out_q, f16* __restrict__ out_k, f16* __restrict__ out_vt,
    float* __restrict__ out_f) {
    const int chunk = gridDim.x >> 3;
    const int hw  = blockIdx.x;
    const int lin = (hw & 7) * chunk + (hw >> 3);
    const int n0  = (lin & 3) * 128;
    const int m0  = ((lin >> 2) & 63) * 128;
    const int z   = QKV ? (lin >> 8) : 0;

    const f16* __restrict__ Bt = Bt_base + (size_t)z * (DM * DM);
    const float* __restrict__ bias = QKV ? (z == 0 ? b0 : z == 1 ? b1 : b2) : b0;

    __shared__ f16 As[2][128 * 64];
    __shared__ f16 Bs[2][128 * 64];

    const int tid  = threadIdx.x;
    const int wid  = tid >> 6;
    const int lane = tid & 63;
    const int l15  = lane & 15;
    const int l4   = lane >> 4;
    const int wr   = wid >> 1, wc = wid & 1;

    floatx4 acc[4][4] = {};
    const int c_ = wid * 64 + lane;

    auto stage = [&](int buf, int k0) {
        #pragma unroll
        for (int i = 0; i < 4; ++i) {
            int c   = i * 256 + c_;
            int row = c >> 3, cw = c & 7;
            int cs  = cw ^ (row & 7);
            const f16* ga = A  + (size_t)(m0 + row) * DM + k0 + cs * 8;
            const f16* gb = Bt + (size_t)(n0 + row) * DM + k0 + cs * 8;
            f16* la = &As[buf][(i * 256 + wid * 64) * 8];
            f16* lb = &Bs[buf][(i * 256 + wid * 64) * 8];
            __builtin_amdgcn_global_load_lds((const GAS void*)ga, (LAS void*)la, 16, 0, 0);
            __builtin_amdgcn_global_load_lds((const GAS void*)gb, (LAS void*)lb, 16, 0, 0);
        }
    };
    auto compute = [&](int buf) {
        #pragma unroll
        for (int ks = 0; ks < 2; ++ks) {
            f16x8 af[4], bfr[4];
            #pragma unroll
            for (int m = 0; m < 4; ++m) {
                int row = wr * 64 + m * 16 + l15;
                int kc  = (ks * 4 + l4) ^ (row & 7);
                af[m] = *(const f16x8*)(&As[buf][row * 64 + kc * 8]);
            }
            #pragma unroll
            for (int n = 0; n < 4; ++n) {
                int row = wc * 64 + n * 16 + l15;
                int kc  = (ks * 4 + l4) ^ (row & 7);
                bfr[n] = *(const f16x8*)(&Bs[buf][row * 64 + kc * 8]);
            }
            #pragma unroll
            for (int m = 0; m < 4; ++m)
                #pragma unroll
                for (int n = 0; n < 4; ++n)
                    acc[m][n] = __builtin_amdgcn_mfma_f32_16x16x32_f16(af[m], bfr[n], acc[m][n], 0, 0, 0);
        }
    };

    stage(0, 0);
    stage(1, 64);
    #pragma unroll
    for (int t = 0; t < 8; ++t) {
        if (t < 7) asm volatile("s_waitcnt vmcnt(8)" ::: "memory");
        else       asm volatile("s_waitcnt vmcnt(0)" ::: "memory");
        __builtin_amdgcn_sched_barrier(0);
        __builtin_amdgcn_s_barrier();
        __builtin_amdgcn_sched_barrier(0);
        compute(t & 1);
        if (t < 6) {
            __builtin_amdgcn_s_barrier();
            __builtin_amdgcn_sched_barrier(0);
            stage(t & 1, (t + 2) * 64);
        }
    }

    #pragma unroll
    for (int n = 0; n < 4; ++n) {
        int gcol = n0 + wc * 64 + n * 16 + l15;
        float bias_v = bias[gcol];
        #pragma unroll
        for (int m = 0; m < 4; ++m) {
            int grow0 = m0 + wr * 64 + m * 16 + l4 * 4;
            #pragma unroll
            for (int r = 0; r < 4; ++r) {
                int grow = grow0 + r;
                float v = acc[m][n][r] + bias_v;
                if constexpr (QKV) {
                    int b = grow >> 11, lp = grow & (LSEQ - 1);
                    int h = gcol >> 6,  d  = gcol & (DH - 1);
                    int bh = b * NH + h;
                    if (z == 0)
                        out_q[((size_t)bh * LSEQ + lp) * DH + d] = (f16)(v * 0.125f);
                    else if (z == 1)
                        out_k[((size_t)bh * LSEQ + lp) * DH + d] = (f16)v;
                    else
                        out_vt[((size_t)bh * DH + d) * LSEQ + lp] = (f16)v;
                } else {
                    out_f[(size_t)grow * DM + gcol] = v;
                }
            }
        }
    }
}

// ---------------------------------------------------------------- windowed attention
__global__ __launch_bounds__(256) void attn_kernel(const f16* __restrict__ Qb,
                                                   const f16* __restrict__ Kb,
                                                   const f16* __restrict__ Vt,
                                                   f16* __restrict__ Ob) {
    const int hw  = blockIdx.x;
    const int lin = (hw & 7) * 128 + (hw >> 3);
    const int bh    = lin >> 5;
    const int q0blk = (lin & 31) * 64;
    const int wid    = threadIdx.x >> 6;
    const int lane   = threadIdx.x & 63;
    const int l15    = lane & 15, l4 = lane >> 4;
    const int qbase  = q0blk + wid * 16;
    const int kstart = q0blk - WIN;

    const f16* __restrict__ Q = Qb + (size_t)bh * LSEQ * DH;
    const f16* __restrict__ K = Kb + (size_t)bh * LSEQ * DH;
    const f16* __restrict__ V = Vt + (size_t)bh * DH * LSEQ;

    __shared__ f16 Pl[4][16][232];

    f16x8 qf[2];
    #pragma unroll
    for (int ks = 0; ks < 2; ++ks)
        qf[ks] = *(const f16x8*)(Q + (size_t)(qbase + l15) * DH + ks * 32 + l4 * 8);

    floatx4 sc[12] = {};
    #pragma unroll
    for (int nt = 0; nt < 12; ++nt) {
        int key = kstart + nt * 16 + l15;
        int kcl = key < 0 ? 0 : (key > LSEQ - 1 ? LSEQ - 1 : key);
        #pragma unroll
        for (int ks = 0; ks < 2; ++ks) {
            f16x8 kf = *(const f16x8*)(K + (size_t)kcl * DH + ks * 32 + l4 * 8);
            sc[nt] = __builtin_amdgcn_mfma_f32_16x16x32_f16(qf[ks], kf, sc[nt], 0, 0, 0);
        }
    }

    float mx[4] = {-1e30f, -1e30f, -1e30f, -1e30f};
    #pragma unroll
    for (int nt = 0; nt < 12; ++nt) {
        int key = kstart + nt * 16 + l15;
        #pragma unroll
        for (int r = 0; r < 4; ++r) {
            int q = qbase + l4 * 4 + r;
            int dist = key - q; dist = dist < 0 ? -dist : dist;
            bool valid = (key >= 0) && (key < LSEQ) && (dist <= WIN);
            float s = valid ? sc[nt][r] : -1e30f;
            sc[nt][r] = s;
            mx[r] = fmaxf(mx[r], s);
        }
    }
    #pragma unroll
    for (int r = 0; r < 4; ++r)
        #pragma unroll
        for (int m = 1; m < 16; m <<= 1)
            mx[r] = fmaxf(mx[r], __shfl_xor(mx[r], m, 64));
    float sm[4] = {0.f, 0.f, 0.f, 0.f};
    #pragma unroll
    for (int nt = 0; nt < 12; ++nt)
        #pragma unroll
        for (int r = 0; r < 4; ++r) {
            float p = __expf(sc[nt][r] - mx[r]);
            sc[nt][r] = p;
            sm[r] += p;
        }
    #pragma unroll
    for (int r = 0; r < 4; ++r) {
        #pragma unroll
        for (int m = 1; m < 16; m <<= 1)
            sm[r] += __shfl_xor(sm[r], m, 64);
        sm[r] = 1.f / sm[r];
    }

    #pragma unroll
    for (int nt = 0; nt < 12; ++nt)
        #pragma unroll
        for (int r = 0; r < 4; ++r)
            Pl[wid][l4 * 4 + r][nt * 16 + l15] = (f16)(sc[nt][r] * sm[r]);
    __syncthreads();

    floatx4 oc[4] = {};
    #pragma unroll
    for (int ks = 0; ks < 6; ++ks) {
        f16x8 pf = *(const f16x8*)(&Pl[wid][l15][ks * 32 + l4 * 8]);
        int kb0 = kstart + ks * 32 + l4 * 8;
        int kbc = (kb0 < 0 || kb0 > LSEQ - 8) ? 0 : kb0;
        #pragma unroll
        for (int dt = 0; dt < 4; ++dt) {
            f16x8 vf = *(const f16x8*)(V + (size_t)(dt * 16 + l15) * LSEQ + kbc);
            oc[dt] = __builtin_amdgcn_mfma_f32_16x16x32_f16(pf, vf, oc[dt], 0, 0, 0);
        }
    }

    int b = bh >> 3, h = bh & 7;
    #pragma unroll
    for (int dt = 0; dt < 4; ++dt) {
        int d = dt * 16 + l15;
        #pragma unroll
        for (int r = 0; r < 4; ++r) {
            int q = qbase + l4 * 4 + r;
            Ob[((size_t)b * LSEQ + q) * DM + h * DH + d] = (f16)oc[dt][r];
        }
    }
}

// ================================================================ DIAGNOSTIC PROBES
// All write only to dead scratch (ws+64MB..). They run AFTER the real pipeline.

// P1: pure MFMA rate + clock sanity. 24 reps x 512 MFMA/wave. Healthy ~50 us.
__global__ __launch_bounds__(512) void probe_mfma(float* __restrict__ scr) {
    int tid = threadIdx.x, lane = tid & 63;
    f16x8 af[8], bf[4];
    #pragma unroll
    for (int j = 0; j < 8; ++j)
        #pragma unroll
        for (int e = 0; e < 8; ++e) af[j][e] = (f16)((lane + j + e) & 7);
    #pragma unroll
    for (int j = 0; j < 4; ++j)
        #pragma unroll
        for (int e = 0; e < 8; ++e) bf[j][e] = (f16)((lane * 2 + j - e) & 7);
    floatx4 acc[8][4] = {};
    #pragma unroll 1
    for (int rep = 0; rep < 24; ++rep) {
        #pragma unroll 1
        for (int t = 0; t < 8; ++t) {
            #pragma unroll
            for (int ks = 0; ks < 2; ++ks)
                #pragma unroll
                for (int m = 0; m < 8; ++m)
                    #pragma unroll
                    for (int n = 0; n < 4; ++n)
                        acc[m][n] = __builtin_amdgcn_mfma_f32_16x16x32_f16(af[m], bf[n], acc[m][n], 0, 0, 0);
        }
    }
    float s = 0.f;
    #pragma unroll
    for (int m = 0; m < 8; ++m)
        #pragma unroll
        for (int n = 0; n < 4; ++n) s += acc[m][n][0] + acc[m][n][3];
    scr[blockIdx.x * 512 + tid] = s;
}

// P2: global_load_lds staging path, exact R9 rhythm (counted vmcnt + barriers),
// no MFMA. 4 reps x 8 K-steps. Healthy <=40 us; pathological ~250.
__global__ __launch_bounds__(512) void probe_stage(const f16* __restrict__ A,
                                                   const f16* __restrict__ Bt,
                                                   float* __restrict__ scr) {
    __shared__ f16 As[2][256 * 64];
    __shared__ f16 Bs[2][256 * 64];
    const int tid = threadIdx.x, wid = tid >> 6;
    const int m0 = (blockIdx.x % 32) * 256;
    auto stage = [&](int buf, int k0) {
        #pragma unroll
        for (int i = 0; i < 4; ++i) {
            int c = i * 512 + tid;
            int row = c >> 3, cw = c & 7;
            int cs = cw ^ (row & 7);
            const f16* ga = A + (size_t)(m0 + row) * DM + k0 + cs * 8;
            f16* la = &As[buf][(i * 512 + wid * 64) * 8];
            __builtin_amdgcn_global_load_lds((const GAS void*)ga, (LAS void*)la, 16, 0, 0);
        }
        #pragma unroll
        for (int i = 0; i < 4; ++i) {
            int c = i * 512 + tid;
            int row = c >> 3, cw = c & 7;
            int cs = cw ^ (row & 7);
            const f16* gb = Bt + (size_t)row * DM + k0 + cs * 8;
            f16* lb = &Bs[buf][(i * 512 + wid * 64) * 8];
            __builtin_amdgcn_global_load_lds((const GAS void*)gb, (LAS void*)lb, 16, 0, 0);
        }
    };
    float v = 0.f;
    #pragma unroll 1
    for (int rep = 0; rep < 4; ++rep) {
        stage(0, 0);
        stage(1, 64);
        #pragma unroll 1
        for (int t = 0; t < 8; ++t) {
            if (t < 7) asm volatile("s_waitcnt vmcnt(8)" ::: "memory");
            else       asm volatile("s_waitcnt vmcnt(0)" ::: "memory");
            __builtin_amdgcn_sched_barrier(0);
            __builtin_amdgcn_s_barrier();
            __builtin_amdgcn_sched_barrier(0);
            v += (float)As[t & 1][tid * 8] + (float)Bs[t & 1][tid * 8];
            if (t < 6) {
                __builtin_amdgcn_s_barrier();
                __builtin_amdgcn_sched_barrier(0);
                stage(t & 1, (t + 2) * 64);
            }
        }
    }
    scr[blockIdx.x * 512 + tid] = v;
}

// P3: R8-style 16-line gathers, VALU-consumed (no MFMA). 4 reps x 16 steps x 8 loads.
// Healthy ~40-60 us; pathological ~250.
__global__ __launch_bounds__(512) void probe_gather(const f16* __restrict__ A,
                                                    const f16* __restrict__ Bt,
                                                    float* __restrict__ scr) {
    const int tid = threadIdx.x, wid = tid >> 6, lane = tid & 63;
    const int l15 = lane & 15, l4 = lane >> 4;
    const int rbase = (blockIdx.x % 32) * 256 + (wid & 3) * 64;
    f16x8 s[8] = {};
    #pragma unroll 1
    for (int rep = 0; rep < 4; ++rep) {
        #pragma unroll 1
        for (int ks = 0; ks < 16; ++ks) {
            int ke = (ks + rep * 4) & 15;
            #pragma unroll
            for (int m = 0; m < 4; ++m)
                s[m] += *(const f16x8*)(A + (size_t)(rbase + m * 16 + l15) * DM + ke * 32 + l4 * 8);
            #pragma unroll
            for (int n = 0; n < 4; ++n)
                s[4 + n] += *(const f16x8*)(Bt + (size_t)((wid * 64 + n * 16 + l15) & 511) * DM + ke * 32 + l4 * 8);
        }
    }
    float v = 0.f;
    #pragma unroll
    for (int j = 0; j < 8; ++j)
        #pragma unroll
        for (int e = 0; e < 8; ++e) v += (float)s[j][e];
    scr[blockIdx.x * 512 + tid] = v;
}

// P4: same gathers, MFMA-consumed (R8 composition). Healthy ~60-70 us; if P3 is
// healthy and this is ~200+, the load->MFMA dependency stall is proven.
__global__ __launch_bounds__(512) void probe_gather_mfma(const f16* __restrict__ A,
                                                         const f16* __restrict__ Bt,
                                                         float* __restrict__ scr) {
    const int tid = threadIdx.x, wid = tid >> 6, lane = tid & 63;
    const int l15 = lane & 15, l4 = lane >> 4;
    const int rbase = (blockIdx.x % 32) * 256 + (wid & 3) * 64;
    floatx4 acc[4][4] = {};
    #pragma unroll 1
    for (int rep = 0; rep < 4; ++rep) {
        #pragma unroll 1
        for (int ks = 0; ks < 16; ++ks) {
            int ke = (ks + rep * 4) & 15;
            f16x8 af[4], bf[4];
            #pragma unroll
            for (int m = 0; m < 4; ++m)
                af[m] = *(const f16x8*)(A + (size_t)(rbase + m * 16 + l15) * DM + ke * 32 + l4 * 8);
            #pragma unroll
            for (int n = 0; n < 4; ++n)
                bf[n] = *(const f16x8*)(Bt + (size_t)((wid * 64 + n * 16 + l15) & 511) * DM + ke * 32 + l4 * 8);
            #pragma unroll
            for (int m = 0; m < 4; ++m)
                #pragma unroll
                for (int n = 0; n < 4; ++n)
                    acc[m][n] = __builtin_amdgcn_mfma_f32_16x16x32_f16(af[m], bf[n], acc[m][n], 0, 0, 0);
        }
    }
    float v = 0.f;
    #pragma unroll
    for (int m = 0; m < 4; ++m)
        #pragma unroll
        for (int n = 0; n < 4; ++n) v += acc[m][n][0] + acc[m][n][2];
    scr[blockIdx.x * 512 + tid] = v;
}

// P5: epilogue store path alone (exact Q/K/Vt scatter), 4 reps. Healthy <42 us
// (absent from top-5); pathological >=100 (present).
__global__ __launch_bounds__(256) void probe_epi(f16* __restrict__ sq,
                                                 f16* __restrict__ sk,
                                                 f16* __restrict__ sv) {
    const int lin = blockIdx.x;
    const int n0 = (lin & 3) * 128;
    const int m0 = ((lin >> 2) & 63) * 128;
    const int z  = lin >> 8;
    const int tid = threadIdx.x, wid = tid >> 6, lane = tid & 63;
    const int l15 = lane & 15, l4 = lane >> 4;
    const int wr = wid >> 1, wc = wid & 1;
    #pragma unroll 1
    for (int rep = 0; rep < 4; ++rep) {
        #pragma unroll
        for (int n = 0; n < 4; ++n) {
            int gcol = n0 + wc * 64 + n * 16 + l15;
            #pragma unroll
            for (int m = 0; m < 4; ++m) {
                int grow0 = m0 + wr * 64 + m * 16 + l4 * 4;
                #pragma unroll
                for (int r = 0; r < 4; ++r) {
                    int grow = grow0 + r;
                    f16 v = (f16)((lane + m * 3 + n + r + rep) & 15);
                    int b = grow >> 11, lp = grow & (LSEQ - 1);
                    int h = gcol >> 6, d = gcol & (DH - 1);
                    int bh = b * NH + h;
                    if (z == 0)      sq[((size_t)bh * LSEQ + lp) * DH + d] = v;
                    else if (z == 1) sk[((size_t)bh * LSEQ + lp) * DH + d] = v;
                    else             sv[((size_t)bh * DH + d) * LSEQ + lp] = v;
                }
            }
        }
    }
}

// ---------------------------------------------------------------- launch
extern "C" void kernel_launch(void* const* d_in, const int* in_sizes, int n_in,
                              void* d_out, int out_size, void* d_ws, size_t ws_size,
                              hipStream_t stream) {
    const float* x  = (const float*)d_in[0];
    const float* Wq = (const float*)d_in[1];
    const float* bq = (const float*)d_in[2];
    const float* Wk = (const float*)d_in[3];
    const float* bk = (const float*)d_in[4];
    const float* Wv = (const float*)d_in[5];
    const float* bv = (const float*)d_in[6];
    const float* Wo = (const float*)d_in[7];
    const float* bo = (const float*)d_in[8];
    float* out = (float*)d_out;

    char* ws = (char*)d_ws;
    f16* xb = (f16*)(ws);                       // 8 MB
    f16* wt = (f16*)(ws + (8ull << 20));        // 2 MB
    f16* qb = (f16*)(ws + (10ull << 20));       // 8 MB
    f16* kb = (f16*)(ws + (18ull << 20));       // 8 MB
    f16* vt = (f16*)(ws + (26ull << 20));       // 8 MB
    f16* ob = (f16*)(ws + (34ull << 20));       // 8 MB
    float* scr  = (float*)(ws + (64ull << 20)); // probe scratch
    f16*   sq   = (f16*)(ws + (96ull << 20));
    f16*   sk   = (f16*)(ws + (104ull << 20));
    f16*   sv   = (f16*)(ws + (112ull << 20));

    // ---- real pipeline (R5 best-known config)
    prep_kernel<<<dim3(5120), 256, 0, stream>>>(x, xb, Wq, Wk, Wv, Wo, wt);
    gemm_kernel<true><<<dim3(768), 256, 0, stream>>>(
        xb, wt, bq, bk, bv, qb, kb, vt, nullptr);
    attn_kernel<<<dim3(1024), 256, 0, stream>>>(qb, kb, vt, ob);
    gemm_kernel<false><<<dim3(256), 256, 0, stream>>>(
        ob, wt + 3ull * DM * DM, bo, bo, bo, nullptr, nullptr, nullptr, out);

    // ---- diagnostic probes (write only to dead scratch)
    probe_mfma<<<dim3(192), 512, 0, stream>>>(scr);
    probe_stage<<<dim3(192), 512, 0, stream>>>(xb, wt, scr);
    probe_gather<<<dim3(192), 512, 0, stream>>>(xb, wt, scr);
    probe_gather_mfma<<<dim3(192), 512, 0, stream>>>(xb, wt, scr);
    probe_epi<<<dim3(768), 256, 0, stream>>>(sq, sk, sv);
}

// Round 11
// 93.514 us; speedup vs baseline: 5.8981x; 5.8981x over previous
//
#include <hip/hip_runtime.h>
#include <cstdint>
#include <cstddef>

typedef _Float16 f16;
typedef f16 f16x8 __attribute__((ext_vector_type(8)));
typedef f16 f16x4 __attribute__((ext_vector_type(4)));
typedef float floatx4 __attribute__((ext_vector_type(4)));

#define GAS __attribute__((address_space(1)))
#define LAS __attribute__((address_space(3)))

static constexpr int LSEQ = 2048;
static constexpr int NH   = 8;
static constexpr int DH   = 64;
static constexpr int DM   = 512;
static constexpr int WIN  = 64;
static constexpr int MR   = 4 * LSEQ;  // 8192 rows (B*L)

// ------------------------------------------- prep: cast x->f16  +  transpose W->f16
__global__ __launch_bounds__(256) void prep_kernel(
    const float* __restrict__ x, f16* __restrict__ xb,
    const float* __restrict__ Wq, const float* __restrict__ Wk,
    const float* __restrict__ Wv, const float* __restrict__ Wo,
    f16* __restrict__ wt) {
    __shared__ float tile[32][33];
    int bid = blockIdx.x;
    if (bid < 4096) {
        int i = bid * 256 + threadIdx.x;
        float4 v = ((const float4*)x)[i];
        f16x4 o = { (f16)v.x, (f16)v.y, (f16)v.z, (f16)v.w };
        ((f16x4*)xb)[i] = o;
    } else {
        int id = bid - 4096;
        int z  = id >> 8, t = id & 255;
        const float* W = z == 0 ? Wq : z == 1 ? Wk : z == 2 ? Wv : Wo;
        f16* out = wt + (size_t)z * DM * DM;
        int c0 = (t & 15) * 32, r0 = (t >> 4) * 32;
        int tx = threadIdx.x & 31, ty = threadIdx.x >> 5;
        #pragma unroll
        for (int i = 0; i < 32; i += 8)
            tile[ty + i][tx] = W[(size_t)(r0 + ty + i) * DM + c0 + tx];
        __syncthreads();
        #pragma unroll
        for (int i = 0; i < 32; i += 8)
            out[(size_t)(c0 + ty + i) * DM + r0 + tx] = (f16)tile[tx][ty + i];
    }
}

// ===================================================== QKV GEMM: 8-phase 256^2 port
// 512 thr (8 waves, 2M x 4N), wave tile 128x64, BK=64, K=512 -> 8 K-tiles.
// LDS 128KB: As[dbuf][half][128*64], Bs likewise (half = 128 rows of the 256-tile).
// Per K-tile t (dbuf t&1): 4 phases; phase p computes m-frags {2p,2p+1} x 4 n x 2 kk
// = 16 MFMA. B-frags (8) loaded at p0, register-reused p1-3. Tile t+1 staged into
// dbuf^1 at p0 (A halves) and p1 (B halves); its vmcnt(0) gate sits at p3's TAIL --
// ~3 phases of MFMA between issue and gate (the lever every prior round lacked).
// XOR-swizzle pair (rule #21): source granule cs = cw ^ (row&7); ds_read applies
// the same XOR. T5 setprio around the MFMA cluster; rule-18 fences after waitcnts.
__global__ __launch_bounds__(512, 1) void gemm_qkv8(
    const f16* __restrict__ A, const f16* __restrict__ Bt_base,
    const float* __restrict__ b0, const float* __restrict__ b1,
    const float* __restrict__ b2,
    f16* __restrict__ out_q, f16* __restrict__ out_k, f16* __restrict__ out_vt) {
    const int hw  = blockIdx.x;
    const int lin = (hw & 7) * 24 + (hw >> 3);   // 192 = 8 XCD x 24, bijective
    const int z   = lin / 64;                    // 0..2
    const int rem = lin % 64;
    const int m0  = (rem >> 1) * 256;            // 32 m-tiles
    const int n0  = (rem & 1) * 256;             // 2 n-tiles

    const f16* __restrict__ Bt = Bt_base + (size_t)z * DM * DM;
    const float* __restrict__ bias = z == 0 ? b0 : z == 1 ? b1 : b2;

    __shared__ f16 As[2][2][128 * 64];   // 64 KB
    __shared__ f16 Bs[2][2][128 * 64];   // 64 KB

    const int tid  = threadIdx.x;
    const int wid  = tid >> 6;
    const int lane = tid & 63;
    const int l15  = lane & 15;
    const int l4   = lane >> 4;
    const int wrow = wid >> 2;           // 0..1 -> A half this wave consumes
    const int wcol = wid & 3;            // 0..3
    const int bh_  = wcol >> 1;          // B half this wave consumes
    const int bcl_ = (wcol & 1) * 64;    // local col base within B half

    floatx4 acc[8][4] = {};

    auto stageA = [&](int db, int h, int k0) {
        #pragma unroll
        for (int r = 0; r < 2; ++r) {
            int c   = r * 512 + tid;             // granule in 128x8 grid
            int row = c >> 3, cw = c & 7;
            int cs  = cw ^ (row & 7);
            const f16* g = A + (size_t)(m0 + h * 128 + row) * DM + k0 + cs * 8;
            f16* l = &As[db][h][(r * 512 + wid * 64) * 8];   // +lane*16B by HW
            __builtin_amdgcn_global_load_lds((const GAS void*)g, (LAS void*)l, 16, 0, 0);
        }
    };
    auto stageB = [&](int db, int h, int k0) {
        #pragma unroll
        for (int r = 0; r < 2; ++r) {
            int c   = r * 512 + tid;
            int row = c >> 3, cw = c & 7;
            int cs  = cw ^ (row & 7);
            const f16* g = Bt + (size_t)(n0 + h * 128 + row) * DM + k0 + cs * 8;
            f16* l = &Bs[db][h][(r * 512 + wid * 64) * 8];
            __builtin_amdgcn_global_load_lds((const GAS void*)g, (LAS void*)l, 16, 0, 0);
        }
    };

    // prologue: tile 0 -> dbuf 0, full drain once
    stageA(0, 0, 0); stageA(0, 1, 0); stageB(0, 0, 0); stageB(0, 1, 0);
    asm volatile("s_waitcnt vmcnt(0)" ::: "memory");
    __builtin_amdgcn_sched_barrier(0);
    __builtin_amdgcn_s_barrier();

    f16x8 bf[4][2];
    #pragma unroll
    for (int t = 0; t < 8; ++t) {
        const int db  = t & 1;
        const int k0n = (t + 1) * 64;
        #pragma unroll
        for (int p = 0; p < 4; ++p) {
            // ---- ds-load register subtile (reads dbuf db; stable since prev tail barrier)
            if (p == 0) {
                #pragma unroll
                for (int n = 0; n < 4; ++n)
                    #pragma unroll
                    for (int kk = 0; kk < 2; ++kk) {
                        int cl = bcl_ + n * 16 + l15;
                        int kc = (kk * 4 + l4) ^ (cl & 7);
                        bf[n][kk] = *(const f16x8*)(&Bs[db][bh_][cl * 64 + kc * 8]);
                    }
            }
            f16x8 af[2][2];
            #pragma unroll
            for (int mi = 0; mi < 2; ++mi)
                #pragma unroll
                for (int kk = 0; kk < 2; ++kk) {
                    int rl = (p * 2 + mi) * 16 + l15;
                    int kc = (kk * 4 + l4) ^ (rl & 7);
                    af[mi][kk] = *(const f16x8*)(&As[db][wrow][rl * 64 + kc * 8]);
                }
            // ---- stage tile t+1 early (p0: A halves, p1: B halves) into dbuf^1
            if (t < 7) {
                if (p == 0)      { stageA(db ^ 1, 0, k0n); stageA(db ^ 1, 1, k0n); }
                else if (p == 1) { stageB(db ^ 1, 0, k0n); stageB(db ^ 1, 1, k0n); }
            }
            __builtin_amdgcn_s_barrier();
            asm volatile("s_waitcnt lgkmcnt(0)" ::: "memory");
            __builtin_amdgcn_sched_barrier(0);
            __builtin_amdgcn_s_setprio(1);
            #pragma unroll
            for (int mi = 0; mi < 2; ++mi)
                #pragma unroll
                for (int n = 0; n < 4; ++n)
                    #pragma unroll
                    for (int kk = 0; kk < 2; ++kk)
                        acc[p * 2 + mi][n] = __builtin_amdgcn_mfma_f32_16x16x32_f16(
                            af[mi][kk], bf[n][kk], acc[p * 2 + mi][n], 0, 0, 0);
            __builtin_amdgcn_s_setprio(0);
            if (p == 3) {   // gate tile t+1 (issued p0/p1: ~3 phases of lead)
                asm volatile("s_waitcnt vmcnt(0)" ::: "memory");
                __builtin_amdgcn_sched_barrier(0);
            }
            __builtin_amdgcn_s_barrier();
        }
    }

    // epilogue; D layout: col = lane&15, row = (lane>>4)*4 + r  (m89-verified)
    #pragma unroll
    for (int n = 0; n < 4; ++n) {
        int gcol = n0 + wcol * 64 + n * 16 + l15;
        float bias_v = bias[gcol];
        #pragma unroll
        for (int m = 0; m < 8; ++m) {
            int grow0 = m0 + wrow * 128 + m * 16 + l4 * 4;
            #pragma unroll
            for (int r = 0; r < 4; ++r) {
                int grow = grow0 + r;
                float v = acc[m][n][r] + bias_v;
                int b = grow >> 11, lp = grow & (LSEQ - 1);
                int h = gcol >> 6,  d  = gcol & (DH - 1);
                int bh = b * NH + h;
                if (z == 0)       // Q, pre-scaled by 1/sqrt(Dh)
                    out_q[((size_t)bh * LSEQ + lp) * DH + d] = (f16)(v * 0.125f);
                else if (z == 1)  // K
                    out_k[((size_t)bh * LSEQ + lp) * DH + d] = (f16)v;
                else              // V transposed [bh][d][l]
                    out_vt[((size_t)bh * DH + d) * LSEQ + lp] = (f16)v;
            }
        }
    }
}

// ---------------------------------------------------------------- out-proj (R5 form)
__global__ __launch_bounds__(256, 2) void gemm_out(
    const f16* __restrict__ A, const f16* __restrict__ Bt,
    const float* __restrict__ bo, float* __restrict__ out_f) {
    const int chunk = gridDim.x >> 3;
    const int hw  = blockIdx.x;
    const int lin = (hw & 7) * chunk + (hw >> 3);
    const int n0  = (lin & 3) * 128;
    const int m0  = ((lin >> 2) & 63) * 128;

    __shared__ f16 As[2][128 * 64];
    __shared__ f16 Bs[2][128 * 64];

    const int tid  = threadIdx.x;
    const int wid  = tid >> 6;
    const int lane = tid & 63;
    const int l15  = lane & 15;
    const int l4   = lane >> 4;
    const int wr   = wid >> 1, wc = wid & 1;

    floatx4 acc[4][4] = {};
    const int c_ = wid * 64 + lane;

    auto stage = [&](int buf, int k0) {
        #pragma unroll
        for (int i = 0; i < 4; ++i) {
            int c   = i * 256 + c_;
            int row = c >> 3, cw = c & 7;
            int cs  = cw ^ (row & 7);
            const f16* ga = A  + (size_t)(m0 + row) * DM + k0 + cs * 8;
            const f16* gb = Bt + (size_t)(n0 + row) * DM + k0 + cs * 8;
            f16* la = &As[buf][(i * 256 + wid * 64) * 8];
            f16* lb = &Bs[buf][(i * 256 + wid * 64) * 8];
            __builtin_amdgcn_global_load_lds((const GAS void*)ga, (LAS void*)la, 16, 0, 0);
            __builtin_amdgcn_global_load_lds((const GAS void*)gb, (LAS void*)lb, 16, 0, 0);
        }
    };
    auto compute = [&](int buf) {
        #pragma unroll
        for (int ks = 0; ks < 2; ++ks) {
            f16x8 af[4], bfr[4];
            #pragma unroll
            for (int m = 0; m < 4; ++m) {
                int row = wr * 64 + m * 16 + l15;
                int kc  = (ks * 4 + l4) ^ (row & 7);
                af[m] = *(const f16x8*)(&As[buf][row * 64 + kc * 8]);
            }
            #pragma unroll
            for (int n = 0; n < 4; ++n) {
                int row = wc * 64 + n * 16 + l15;
                int kc  = (ks * 4 + l4) ^ (row & 7);
                bfr[n] = *(const f16x8*)(&Bs[buf][row * 64 + kc * 8]);
            }
            #pragma unroll
            for (int m = 0; m < 4; ++m)
                #pragma unroll
                for (int n = 0; n < 4; ++n)
                    acc[m][n] = __builtin_amdgcn_mfma_f32_16x16x32_f16(af[m], bfr[n], acc[m][n], 0, 0, 0);
        }
    };

    stage(0, 0);
    stage(1, 64);
    #pragma unroll
    for (int t = 0; t < 8; ++t) {
        if (t < 7) asm volatile("s_waitcnt vmcnt(8)" ::: "memory");
        else       asm volatile("s_waitcnt vmcnt(0)" ::: "memory");
        __builtin_amdgcn_sched_barrier(0);
        __builtin_amdgcn_s_barrier();
        __builtin_amdgcn_sched_barrier(0);
        compute(t & 1);
        if (t < 6) {
            __builtin_amdgcn_s_barrier();
            __builtin_amdgcn_sched_barrier(0);
            stage(t & 1, (t + 2) * 64);
        }
    }

    #pragma unroll
    for (int n = 0; n < 4; ++n) {
        int gcol = n0 + wc * 64 + n * 16 + l15;
        float bias_v = bo[gcol];
        #pragma unroll
        for (int m = 0; m < 4; ++m) {
            int grow0 = m0 + wr * 64 + m * 16 + l4 * 4;
            #pragma unroll
            for (int r = 0; r < 4; ++r)
                out_f[(size_t)(grow0 + r) * DM + gcol] = acc[m][n][r] + bias_v;
        }
    }
}

// ---------------------------------------------------------------- windowed attention
__global__ __launch_bounds__(256) void attn_kernel(const f16* __restrict__ Qb,
                                                   const f16* __restrict__ Kb,
                                                   const f16* __restrict__ Vt,
                                                   f16* __restrict__ Ob) {
    const int hw  = blockIdx.x;
    const int lin = (hw & 7) * 128 + (hw >> 3);
    const int bh    = lin >> 5;
    const int q0blk = (lin & 31) * 64;
    const int wid    = threadIdx.x >> 6;
    const int lane   = threadIdx.x & 63;
    const int l15    = lane & 15, l4 = lane >> 4;
    const int qbase  = q0blk + wid * 16;
    const int kstart = q0blk - WIN;

    const f16* __restrict__ Q = Qb + (size_t)bh * LSEQ * DH;
    const f16* __restrict__ K = Kb + (size_t)bh * LSEQ * DH;
    const f16* __restrict__ V = Vt + (size_t)bh * DH * LSEQ;

    __shared__ f16 Pl[4][16][232];

    f16x8 qf[2];
    #pragma unroll
    for (int ks = 0; ks < 2; ++ks)
        qf[ks] = *(const f16x8*)(Q + (size_t)(qbase + l15) * DH + ks * 32 + l4 * 8);

    floatx4 sc[12] = {};
    #pragma unroll
    for (int nt = 0; nt < 12; ++nt) {
        int key = kstart + nt * 16 + l15;
        int kcl = key < 0 ? 0 : (key > LSEQ - 1 ? LSEQ - 1 : key);
        #pragma unroll
        for (int ks = 0; ks < 2; ++ks) {
            f16x8 kf = *(const f16x8*)(K + (size_t)kcl * DH + ks * 32 + l4 * 8);
            sc[nt] = __builtin_amdgcn_mfma_f32_16x16x32_f16(qf[ks], kf, sc[nt], 0, 0, 0);
        }
    }

    float mx[4] = {-1e30f, -1e30f, -1e30f, -1e30f};
    #pragma unroll
    for (int nt = 0; nt < 12; ++nt) {
        int key = kstart + nt * 16 + l15;
        #pragma unroll
        for (int r = 0; r < 4; ++r) {
            int q = qbase + l4 * 4 + r;
            int dist = key - q; dist = dist < 0 ? -dist : dist;
            bool valid = (key >= 0) && (key < LSEQ) && (dist <= WIN);
            float s = valid ? sc[nt][r] : -1e30f;
            sc[nt][r] = s;
            mx[r] = fmaxf(mx[r], s);
        }
    }
    #pragma unroll
    for (int r = 0; r < 4; ++r)
        #pragma unroll
        for (int m = 1; m < 16; m <<= 1)
            mx[r] = fmaxf(mx[r], __shfl_xor(mx[r], m, 64));
    float sm[4] = {0.f, 0.f, 0.f, 0.f};
    #pragma unroll
    for (int nt = 0; nt < 12; ++nt)
        #pragma unroll
        for (int r = 0; r < 4; ++r) {
            float p = __expf(sc[nt][r] - mx[r]);
            sc[nt][r] = p;
            sm[r] += p;
        }
    #pragma unroll
    for (int r = 0; r < 4; ++r) {
        #pragma unroll
        for (int m = 1; m < 16; m <<= 1)
            sm[r] += __shfl_xor(sm[r], m, 64);
        sm[r] = 1.f / sm[r];
    }

    #pragma unroll
    for (int nt = 0; nt < 12; ++nt)
        #pragma unroll
        for (int r = 0; r < 4; ++r)
            Pl[wid][l4 * 4 + r][nt * 16 + l15] = (f16)(sc[nt][r] * sm[r]);
    __syncthreads();

    floatx4 oc[4] = {};
    #pragma unroll
    for (int ks = 0; ks < 6; ++ks) {
        f16x8 pf = *(const f16x8*)(&Pl[wid][l15][ks * 32 + l4 * 8]);
        int kb0 = kstart + ks * 32 + l4 * 8;
        int kbc = (kb0 < 0 || kb0 > LSEQ - 8) ? 0 : kb0;
        #pragma unroll
        for (int dt = 0; dt < 4; ++dt) {
            f16x8 vf = *(const f16x8*)(V + (size_t)(dt * 16 + l15) * LSEQ + kbc);
            oc[dt] = __builtin_amdgcn_mfma_f32_16x16x32_f16(pf, vf, oc[dt], 0, 0, 0);
        }
    }

    int b = bh >> 3, h = bh & 7;
    #pragma unroll
    for (int dt = 0; dt < 4; ++dt) {
        int d = dt * 16 + l15;
        #pragma unroll
        for (int r = 0; r < 4; ++r) {
            int q = qbase + l4 * 4 + r;
            Ob[((size_t)b * LSEQ + q) * DM + h * DH + d] = (f16)oc[dt][r];
        }
    }
}

// ---------------------------------------------------------------- launch
extern "C" void kernel_launch(void* const* d_in, const int* in_sizes, int n_in,
                              void* d_out, int out_size, void* d_ws, size_t ws_size,
                              hipStream_t stream) {
    const float* x  = (const float*)d_in[0];
    const float* Wq = (const float*)d_in[1];
    const float* bq = (const float*)d_in[2];
    const float* Wk = (const float*)d_in[3];
    const float* bk = (const float*)d_in[4];
    const float* Wv = (const float*)d_in[5];
    const float* bv = (const float*)d_in[6];
    const float* Wo = (const float*)d_in[7];
    const float* bo = (const float*)d_in[8];
    float* out = (float*)d_out;

    char* ws = (char*)d_ws;
    f16* xb = (f16*)(ws);                       // 8 MB  [8192][512]
    f16* wt = (f16*)(ws + (8ull << 20));        // 2 MB  WqT,WkT,WvT,WoT
    f16* qb = (f16*)(ws + (10ull << 20));       // 8 MB  [32][2048][64], pre-scaled
    f16* kb = (f16*)(ws + (18ull << 20));       // 8 MB  [32][2048][64]
    f16* vt = (f16*)(ws + (26ull << 20));       // 8 MB  [32][64][2048]
    f16* ob = (f16*)(ws + (34ull << 20));       // 8 MB  [8192][512]

    prep_kernel<<<dim3(5120), 256, 0, stream>>>(x, xb, Wq, Wk, Wv, Wo, wt);
    // QKV: 32 m-tiles x 2 n-tiles x 3 z = 192 blocks of 256x256, 8-phase schedule
    gemm_qkv8<<<dim3(192), 512, 0, stream>>>(xb, wt, bq, bk, bv, qb, kb, vt);
    attn_kernel<<<dim3(1024), 256, 0, stream>>>(qb, kb, vt, ob);
    gemm_out<<<dim3(256), 256, 0, stream>>>(ob, wt + 3ull * DM * DM, bo, out);
}